// Round 1
// baseline (213.927 us; speedup 1.0000x reference)
//
#include <hip/hip_runtime.h>
#include <hip/hip_bf16.h>
#include <cstdint>

// Problem constants (B=16, N=4096, D_IN=D_OUT=64)
#define NB   16
#define NN   4096
#define ND   64
#define NJ   1024   // NB*ND columns of the big GEMM

typedef __attribute__((ext_vector_type(8))) short  short8;  // 8 bf16 = 4 VGPRs (guide §3, gfx950-verified)
typedef __attribute__((ext_vector_type(4))) float  f32x4;

__device__ __forceinline__ unsigned short f2bf(float f) {
  union { float f; unsigned int u; } v; v.f = f;
  unsigned int u = v.u;
  unsigned int r = u + 0x7FFFu + ((u >> 16) & 1u);  // round-to-nearest-even
  return (unsigned short)(r >> 16);
}

// ---------------- K1: A fp32 -> bf16, 8 elems/thread, fully vectorized ----------------
__global__ void k_convert(const float* __restrict__ A, unsigned short* __restrict__ Ab) {
  int idx = blockIdx.x * 256 + threadIdx.x;          // 2,097,152 threads exactly
  const float4* p = (const float4*)A + (size_t)idx * 2;
  float4 a = p[0], b = p[1];
  unsigned int w0 = (unsigned int)f2bf(a.x) | ((unsigned int)f2bf(a.y) << 16);
  unsigned int w1 = (unsigned int)f2bf(a.z) | ((unsigned int)f2bf(a.w) << 16);
  unsigned int w2 = (unsigned int)f2bf(b.x) | ((unsigned int)f2bf(b.y) << 16);
  unsigned int w3 = (unsigned int)f2bf(b.z) | ((unsigned int)f2bf(b.w) << 16);
  uint4 o; o.x = w0; o.y = w1; o.z = w2; o.w = w3;
  ((uint4*)Ab)[idx] = o;                             // 16B store
}

// ---------------- K2: Yt[b*64+e][m] = sum_d Z[b][m][d]*W[d][e], fp32 math -> bf16 ----
// Block: 256 thr = 4 waves; all waves share the same 64 m-rows, each wave owns 16 e's.
// Lane = m-offset -> stores are 64x2B contiguous (coalesced). W via scalar loads.
__global__ void k_zw(const float* __restrict__ Z, const float* __restrict__ W,
                     unsigned short* __restrict__ Yt) {
  int lane = threadIdx.x & 63;
  int e0 = __builtin_amdgcn_readfirstlane((threadIdx.x >> 6) << 4);  // wave-uniform -> s_load W
  int b  = blockIdx.x >> 6;          // [0,16)
  int m0 = (blockIdx.x & 63) << 6;   // [0,4096) step 64
  int m  = m0 + lane;
  const float* zr = Z + ((size_t)b * NN + m) * ND;
  float z[64];
#pragma unroll
  for (int g = 0; g < 16; ++g) *(float4*)&z[g * 4] = ((const float4*)zr)[g];
  float acc[16];
#pragma unroll
  for (int i = 0; i < 16; ++i) acc[i] = 0.f;
#pragma unroll
  for (int d = 0; d < 64; ++d) {
    float zd = z[d];
#pragma unroll
    for (int i = 0; i < 16; ++i) acc[i] += zd * W[d * 64 + e0 + i];  // uniform addr -> SMEM
  }
#pragma unroll
  for (int i = 0; i < 16; ++i)
    Yt[(size_t)(b * 64 + e0 + i) * NN + m] = f2bf(acc[i]);
}

// ---------------- K3: Out += Ab[4096x4096] @ Y (Yt is [j][k], k-contiguous) -----------
// 128x128 tile, BK=64, 4 waves each 64x64 (4x4 16x16x32 MFMA tiles), split-K x2.
// LDS layout [kg][row][8 bf16]: global_load_lds-contiguous AND conflict-free ds_read_b128.
__device__ __forceinline__ void gl2lds16(const unsigned short* g, unsigned short* l) {
  __builtin_amdgcn_global_load_lds(
      (const __attribute__((address_space(1))) unsigned int*)g,
      (__attribute__((address_space(3))) unsigned int*)l, 16, 0, 0);
}

__launch_bounds__(256, 2)
__global__ void k_gemm(const unsigned short* __restrict__ Ab,
                       const unsigned short* __restrict__ Yt,
                       float* __restrict__ out) {
  __shared__ unsigned short lds[16384];  // A tile [0,8192) ushorts, B tile [8192,16384): 32 KB
  int tid = threadIdx.x;
  int w = tid >> 6, lane = tid & 63;
  int quad = lane >> 4, l15 = lane & 15;

  // XCD swizzle: bx%8 = intended XCD; each XCD gets 4 m-strips (all j, both k-chunks).
  int x = blockIdx.x & 7;
  int t = blockIdx.x >> 3;           // [0,64)
  int kc    = t & 1;
  int j_blk = (t >> 1) & 7;
  int m_blk = x * 4 + (t >> 4);
  int mrow0 = m_blk * 128;
  int jcol0 = j_blk * 128;
  int kbase = kc * 2048;

  int wrow = (w >> 1) * 64, wcol = (w & 1) * 64;

  f32x4 acc[4][4];
#pragma unroll
  for (int i = 0; i < 4; ++i)
#pragma unroll
    for (int j = 0; j < 4; ++j) acc[i][j] = (f32x4){0.f, 0.f, 0.f, 0.f};

  for (int kt = 0; kt < 32; ++kt) {
    int k0 = kbase + kt * 64;
    __syncthreads();  // prior iter's LDS reads done before overwrite
    // Stage A tile: 1024 chunks of 16B; chunk c -> kg=c>>7, row=c&127. 4 instr/wave.
#pragma unroll
    for (int i = 0; i < 4; ++i) {
      int c0 = (w * 4 + i) * 64;               // wave-uniform LDS base (chunk index)
      int c  = c0 + lane;
      int kg = c >> 7, row = c & 127;
      gl2lds16(Ab + (size_t)(mrow0 + row) * 4096 + (k0 + kg * 8), &lds[c0 * 8]);
    }
    // Stage B tile from Yt (rows = j, k-contiguous)
#pragma unroll
    for (int i = 0; i < 4; ++i) {
      int c0 = (w * 4 + i) * 64;
      int c  = c0 + lane;
      int kg = c >> 7, jj = c & 127;
      gl2lds16(Yt + (size_t)(jcol0 + jj) * 4096 + (k0 + kg * 8), &lds[8192 + c0 * 8]);
    }
    __syncthreads();  // drains vmcnt (global_load_lds) per barrier semantics
#pragma unroll
    for (int ks = 0; ks < 2; ++ks) {
      int kg = ks * 4 + quad;
      short8 af[4], bf[4];
#pragma unroll
      for (int i = 0; i < 4; ++i) {
        // A frag: lane holds A[m=l15][k=quad*8+0..7] (m120-verified layout)
        af[i] = *(const short8*)&lds[(kg * 128 + wrow + i * 16 + l15) * 8];
        // B frag: lane holds B[k=quad*8+0..7][n=l15]
        bf[i] = *(const short8*)&lds[8192 + (kg * 128 + wcol + i * 16 + l15) * 8];
      }
#pragma unroll
      for (int i = 0; i < 4; ++i)
#pragma unroll
        for (int j = 0; j < 4; ++j)
          acc[i][j] = __builtin_amdgcn_mfma_f32_16x16x32_bf16(af[i], bf[j], acc[i][j], 0, 0, 0);
    }
  }

  // Epilogue: C/D layout col=l15, row=quad*4+reg (m89/m91-verified).
  // out[b][n][e] flat = ((j>>6)*4096 + n)*64 + (j&63); split-K -> atomicAdd (out pre-zeroed).
#pragma unroll
  for (int i = 0; i < 4; ++i) {
    int r0 = mrow0 + wrow + i * 16 + quad * 4;
#pragma unroll
    for (int j = 0; j < 4; ++j) {
      int jc = jcol0 + wcol + j * 16 + l15;
      int bidx = jc >> 6, e = jc & 63;
      float* op = out + ((size_t)bidx * NN + r0) * 64 + e;
#pragma unroll
      for (int rg = 0; rg < 4; ++rg)
        atomicAdd(op + (size_t)rg * 64, acc[i][j][rg]);
    }
  }
}

extern "C" void kernel_launch(void* const* d_in, const int* in_sizes, int n_in,
                              void* d_out, int out_size, void* d_ws, size_t ws_size,
                              hipStream_t stream) {
  const float* Z = (const float*)d_in[0];   // [16][4096][64] fp32
  const float* A = (const float*)d_in[1];   // [4096][4096] fp32
  const float* W = (const float*)d_in[2];   // [64][64] fp32
  float* out = (float*)d_out;               // [16][4096][64] fp32

  unsigned short* Ab = (unsigned short*)d_ws;                                   // 32 MiB bf16 A
  unsigned short* Yt = (unsigned short*)((char*)d_ws + (size_t)32 * 1024 * 1024); // 8 MiB bf16 Y^T

  hipMemsetAsync(d_out, 0, (size_t)out_size * sizeof(float), stream);  // split-K accumulator base
  k_convert<<<8192, 256, 0, stream>>>(A, Ab);
  k_zw<<<1024, 256, 0, stream>>>(Z, W, Yt);
  k_gemm<<<512, 256, 0, stream>>>(Ab, Yt, out);
}

// Round 2
// 201.643 us; speedup vs baseline: 1.0609x; 1.0609x over previous
//
#include <hip/hip_runtime.h>
#include <hip/hip_bf16.h>
#include <cstdint>

// Problem constants (B=16, N=4096, D_IN=D_OUT=64)
#define NB   16
#define NN   4096
#define ND   64
#define NJ   1024   // NB*ND columns of the big GEMM

typedef __attribute__((ext_vector_type(8))) short  short8;  // 8 bf16 = 4 VGPRs
typedef __attribute__((ext_vector_type(4))) float  f32x4;

__device__ __forceinline__ unsigned short f2bf(float f) {
  union { float f; unsigned int u; } v; v.f = f;
  unsigned int u = v.u;
  unsigned int r = u + 0x7FFFu + ((u >> 16) & 1u);  // round-to-nearest-even
  return (unsigned short)(r >> 16);
}

// ---------------- K1: A fp32 -> bf16 (vectorized) + zero d_out (replaces memset) ------
__global__ void k_convert(const float* __restrict__ A, unsigned short* __restrict__ Ab,
                          float* __restrict__ outz) {
  int idx = blockIdx.x * 256 + threadIdx.x;          // 2,097,152 threads exactly
  const float4* p = (const float4*)A + (size_t)idx * 2;
  float4 a = p[0], b = p[1];
  unsigned int w0 = (unsigned int)f2bf(a.x) | ((unsigned int)f2bf(a.y) << 16);
  unsigned int w1 = (unsigned int)f2bf(a.z) | ((unsigned int)f2bf(a.w) << 16);
  unsigned int w2 = (unsigned int)f2bf(b.x) | ((unsigned int)f2bf(b.y) << 16);
  unsigned int w3 = (unsigned int)f2bf(b.z) | ((unsigned int)f2bf(b.w) << 16);
  uint4 o; o.x = w0; o.y = w1; o.z = w2; o.w = w3;
  ((uint4*)Ab)[idx] = o;                             // 16B store
  if (idx < (NB * NN * ND / 4))                      // 1,048,576 float4s = 16 MiB
    ((float4*)outz)[idx] = (float4){0.f, 0.f, 0.f, 0.f};  // split-K accumulator base
}

// ---------------- K2: Yt[b*64+e][m] = sum_d Z[b][m][d]*W[d][e], fp32 math -> bf16 ----
__global__ void k_zw(const float* __restrict__ Z, const float* __restrict__ W,
                     unsigned short* __restrict__ Yt) {
  int lane = threadIdx.x & 63;
  int e0 = __builtin_amdgcn_readfirstlane((threadIdx.x >> 6) << 4);  // wave-uniform -> s_load W
  int b  = blockIdx.x >> 6;          // [0,16)
  int m0 = (blockIdx.x & 63) << 6;   // [0,4096) step 64
  int m  = m0 + lane;
  const float* zr = Z + ((size_t)b * NN + m) * ND;
  float z[64];
#pragma unroll
  for (int g = 0; g < 16; ++g) *(float4*)&z[g * 4] = ((const float4*)zr)[g];
  float acc[16];
#pragma unroll
  for (int i = 0; i < 16; ++i) acc[i] = 0.f;
#pragma unroll
  for (int d = 0; d < 64; ++d) {
    float zd = z[d];
#pragma unroll
    for (int i = 0; i < 16; ++i) acc[i] += zd * W[d * 64 + e0 + i];  // uniform addr -> SMEM
  }
#pragma unroll
  for (int i = 0; i < 16; ++i)
    Yt[(size_t)(b * 64 + e0 + i) * NN + m] = f2bf(acc[i]);
}

// ---------------- K3: Out += Ab[4096x4096] @ Y (Yt is [j][k], k-contiguous) -----------
// 128x128 tile, BK=64, 4 waves each 64x64 (4x4 16x16x32 MFMA tiles), split-K x4.
// LDS: row-major, XOR-swizzled chunk slots: slot(row,kg) = row*8 + (kg ^ (row&7)).
//  - staging: lane-linear slots => per instr 8 rows x 128B fully-contiguous global reads
//  - ds_read_b128: bankgroup = (ks*4+quad)^(l15&7) -> exactly 8 lanes/group (optimal)
__device__ __forceinline__ void gl2lds16(const unsigned short* g, unsigned short* l) {
  __builtin_amdgcn_global_load_lds(
      (const __attribute__((address_space(1))) unsigned int*)g,
      (__attribute__((address_space(3))) unsigned int*)l, 16, 0, 0);
}

__launch_bounds__(256, 4)  // 4 blocks/CU: regs ~60V+64A=124 <= 128/wave, LDS 4x32K=128K
__global__ void k_gemm(const unsigned short* __restrict__ Ab,
                       const unsigned short* __restrict__ Yt,
                       float* __restrict__ out) {
  __shared__ unsigned short lds[16384];  // A tile [0,8192) shorts, B tile [8192,16384): 32 KB
  int tid = threadIdx.x;
  int w = tid >> 6, lane = tid & 63;
  int quad = lane >> 4, l15 = lane & 15;

  // XCD swizzle: bx%8 = XCD. t order: j fastest (8 j-blocks share one A strip in L2),
  // then kc, then m. grid = 8 XCD * 128.
  int x = blockIdx.x & 7;
  int t = blockIdx.x >> 3;           // [0,128)
  int j_blk = t & 7;
  int kc    = (t >> 3) & 3;
  int m_blk = x * 4 + (t >> 5);
  int mrow0 = m_blk * 128;
  int jcol0 = j_blk * 128;
  int kbase = kc * 1024;

  int wrow = (w >> 1) * 64, wcol = (w & 1) * 64;

  // Per-lane kt-invariant staging source offsets (shorts): chunk slot s = c0+lane.
  // row = s>>3, kg = (s&7) ^ (row&7).
  int srcA[4], srcB[4], dst0[4];
#pragma unroll
  for (int i = 0; i < 4; ++i) {
    int c0 = (w * 4 + i) * 64;
    int s  = c0 + lane;
    int row = s >> 3;
    int kg  = (s & 7) ^ (row & 7);
    srcA[i] = row * 4096 + kg * 8;   // + mrow0*4096 + k0 at use
    srcB[i] = row * 4096 + kg * 8;   // row plays the role of jj for B
    dst0[i] = c0 * 8;                // wave-uniform LDS base (shorts)
  }

  // Per-lane ds_read bases (shorts): addr(i,ks) = (row*8 + ((ks*4+quad)^(l15&7)))*8
  //   = l15*64 + ((ks*4+quad)^(l15&7))*8  + (wrow + i*16)*64   [i-part folds to imm offset]
  int rbA0 = (wrow + l15) * 64 + ((quad ^ (l15 & 7)) * 8);
  int rbA1 = (wrow + l15) * 64 + (((4 + quad) ^ (l15 & 7)) * 8);
  int rbB0 = 8192 + (wcol + l15) * 64 + ((quad ^ (l15 & 7)) * 8);
  int rbB1 = 8192 + (wcol + l15) * 64 + (((4 + quad) ^ (l15 & 7)) * 8);

  f32x4 acc[4][4];
#pragma unroll
  for (int i = 0; i < 4; ++i)
#pragma unroll
    for (int j = 0; j < 4; ++j) acc[i][j] = (f32x4){0.f, 0.f, 0.f, 0.f};

  for (int kt = 0; kt < 16; ++kt) {
    int k0 = kbase + kt * 64;
    __syncthreads();  // prior iter's LDS reads done before overwrite
#pragma unroll
    for (int i = 0; i < 4; ++i)
      gl2lds16(Ab + (size_t)mrow0 * 4096 + srcA[i] + k0, &lds[dst0[i]]);
#pragma unroll
    for (int i = 0; i < 4; ++i)
      gl2lds16(Yt + (size_t)jcol0 * 4096 + srcB[i] + k0, &lds[8192 + dst0[i]]);
    __syncthreads();  // drains vmcnt (global_load_lds) per barrier semantics
#pragma unroll
    for (int ks = 0; ks < 2; ++ks) {
      int ba = ks ? rbA1 : rbA0;
      int bb = ks ? rbB1 : rbB0;
      short8 af[4], bf[4];
#pragma unroll
      for (int i = 0; i < 4; ++i) {
        af[i] = *(const short8*)&lds[ba + i * 1024];  // +i*16 rows * 64 shorts
        bf[i] = *(const short8*)&lds[bb + i * 1024];
      }
#pragma unroll
      for (int i = 0; i < 4; ++i)
#pragma unroll
        for (int j = 0; j < 4; ++j)
          acc[i][j] = __builtin_amdgcn_mfma_f32_16x16x32_bf16(af[i], bf[j], acc[i][j], 0, 0, 0);
    }
  }

  // Epilogue: C/D layout col=l15, row=quad*4+reg (m89/m91-verified).
  // out[b][n][e] flat = ((j>>6)*4096 + n)*64 + (j&63); split-K -> atomicAdd (out pre-zeroed).
#pragma unroll
  for (int i = 0; i < 4; ++i) {
    int r0 = mrow0 + wrow + i * 16 + quad * 4;
#pragma unroll
    for (int j = 0; j < 4; ++j) {
      int jc = jcol0 + wcol + j * 16 + l15;
      int bidx = jc >> 6, e = jc & 63;
      float* op = out + ((size_t)bidx * NN + r0) * 64 + e;
#pragma unroll
      for (int rg = 0; rg < 4; ++rg)
        atomicAdd(op + (size_t)rg * 64, acc[i][j][rg]);
    }
  }
}

extern "C" void kernel_launch(void* const* d_in, const int* in_sizes, int n_in,
                              void* d_out, int out_size, void* d_ws, size_t ws_size,
                              hipStream_t stream) {
  const float* Z = (const float*)d_in[0];   // [16][4096][64] fp32
  const float* A = (const float*)d_in[1];   // [4096][4096] fp32
  const float* W = (const float*)d_in[2];   // [64][64] fp32
  float* out = (float*)d_out;               // [16][4096][64] fp32

  unsigned short* Ab = (unsigned short*)d_ws;                                     // 32 MiB bf16 A
  unsigned short* Yt = (unsigned short*)((char*)d_ws + (size_t)32 * 1024 * 1024); // 8 MiB bf16 Y^T

  k_convert<<<8192, 256, 0, stream>>>(A, Ab, out);   // also zeroes out (split-K base)
  k_zw<<<1024, 256, 0, stream>>>(Z, W, Yt);
  k_gemm<<<1024, 256, 0, stream>>>(Ab, Yt, out);
}